// Round 7
// baseline (19.329 us; speedup 1.0000x reference)
//
#include <hip/hip_runtime.h>
#include <math.h>

// ---------------------------------------------------------------------------
// FashionNetLoss: 3-scale YOLO-ish loss.
//  * obj focal loss is a mean over ALL cells, but target is 0 except at the
//    512 occupied cells per scale -> sum focal(x,0) over all cells, then a
//    per-target correction focal(x,t)-focal(x,0).
//  * box & cls losses only involve the 512 occupied cells per scale.
//  * npos == 512 per scale.
//
// R6 post-mortem: kernel work is ~2-4us (L3-resident during replays); the
// ~11us residual is node overhead (dispatch barrier + cross-XCD L2 flush per
// kernel boundary). R7: fuse finalize INTO the main kernel as a consumer
// block using coherence-point atomics only (the mechanism R5 validated):
// producers atomicExch their slots, vmcnt(0), atomicExch a tag; block 0
// spin-polls tags (atomicAdd(,0) reads, s_sleep throttle, bounded), then
// reads slots via atomicAdd(,0.0f). No __threadfence (R3's L2-writeback
// trap), no same-line counter (R3's 13ns-serialized-RMW trap). Tags are
// zeroed each call by a 1-block prologue kernel (2 nodes total, but the
// data-dependent finalize launch+flush is gone).
//
// Worker map (wid=bid-1): [0,6) box (s=gid>>9), [6,84) cls (sk=(wid-6)>>1,
//   s=sk/13), [84,609) sweep chunks: [0,400)=s0, [400,500)=s1, [500,525)=s2.
// ws layout: float slots [2*wid, 2*wid+1]; uint tags at float-index 2048+wid.
// ---------------------------------------------------------------------------

#define NBLK_BOX 6     // 1536 threads: one per (target,scale), ch0..4
#define NBLK_CLS 78    // 19968 threads: one per (target,scale,class)
#define NBLK_TGT (NBLK_BOX + NBLK_CLS)            // 84
#define NBLK_SWEEP 525 // 512 float4 per block, 2 per thread
#define NWORK (NBLK_TGT + NBLK_SWEEP)             // 609 worker blocks
#define TAG_OFF 2048   // float index where uint tags begin

namespace {
// exact path (box blocks only)
__device__ __forceinline__ float bce_logits(float x, float t) {
    return fmaxf(x, 0.0f) - x * t + log1pf(expf(-fabsf(x)));
}
__device__ __forceinline__ float focal_term(float x, float t) {
    float b = bce_logits(x, t);
    float pt = expf(-b);
    float om = fmaxf(1.0f - pt, 0.0f);
    return 0.25f * om * sqrtf(om) * b;   // alpha=0.25, gamma=1.5
}
// fast path (sweep + cls): v_exp_f32 / v_log_f32 based
__device__ __forceinline__ float softplus_neg(float u) {  // log1p(exp(u)), u<=0
    return __logf(1.0f + __expf(u));
}
__device__ __forceinline__ float bce_fast(float x, float t) {
    return fmaxf(x, 0.0f) - x * t + softplus_neg(-fabsf(x));
}
__device__ __forceinline__ float focal0_fast(float x) {   // focal(x, 0)
    float b = fmaxf(x, 0.0f) + softplus_neg(-fabsf(x));
    float pt = __expf(-b);
    float om = fmaxf(1.0f - pt, 0.0f);
    return 0.25f * om * sqrtf(om) * b;
}
} // namespace

// Prologue node: zero the 609 tags (tiny dirty footprint -> cheap flush).
__global__ void fnl_zero_tags(unsigned* __restrict__ wsU) {
    int i = threadIdx.x;
    if (i < NWORK) wsU[TAG_OFF + i] = 0u;
}

__global__ void __launch_bounds__(256) fnl_fused(
    const float* __restrict__ p0, const float* __restrict__ p1,
    const float* __restrict__ p2, const float* __restrict__ tg,
    float* __restrict__ ws, float* __restrict__ out) {
    unsigned* tags = reinterpret_cast<unsigned*>(ws) + TAG_OFF;

    if (blockIdx.x == 0) {
        // ================= consumer / finalizer block ======================
        // Spin until all 609 tags are set this call. Each thread owns up to
        // 3 tags; once a tag is seen set it is never re-polled. Bounded.
        int i0 = threadIdx.x, i1 = threadIdx.x + 256, i2 = threadIdx.x + 512;
        bool d0 = false, d1 = (i1 >= NWORK), d2 = (i2 >= NWORK);
        for (int it = 0; it < 1000000 && !(d0 && d1 && d2); ++it) {
            if (!d0) d0 = (atomicAdd(&tags[i0], 0u) != 0u);
            if (!d1) d1 = (atomicAdd(&tags[i1], 0u) != 0u);
            if (!d2) d2 = (atomicAdd(&tags[i2], 0u) != 0u);
            if (!(d0 && d1 && d2)) __builtin_amdgcn_s_sleep(2);
        }
        __syncthreads();

        // acc layout: [s*4 + {0:focal,1:box,2:cls,3:corr}]
        float a[12];
        #pragma unroll
        for (int j = 0; j < 12; ++j) a[j] = 0.0f;

        for (int i = threadIdx.x; i < NWORK; i += 256) {
            float v0 = atomicAdd(&ws[2 * i + 0], 0.0f);  // coherence-pt read
            float v1 = atomicAdd(&ws[2 * i + 1], 0.0f);
            if (i < NBLK_BOX) {
                int s = i >> 1;
                a[s * 4 + 1] += v0;
                a[s * 4 + 3] += v1;
            } else if (i < NBLK_TGT) {
                int sk = (i - NBLK_BOX) >> 1;
                int s = sk / 13;
                a[s * 4 + 2] += v0;
            } else {
                int chunk = i - NBLK_TGT;
                int s = (chunk < 400) ? 0 : ((chunk < 500) ? 1 : 2);
                a[s * 4 + 0] += v0;
            }
        }

        __shared__ float red[12];
        if (threadIdx.x < 12) red[threadIdx.x] = 0.0f;
        __syncthreads();
        #pragma unroll
        for (int j = 0; j < 12; ++j) {
            float v = a[j];
            for (int off = 32; off; off >>= 1) v += __shfl_down(v, off);
            if ((threadIdx.x & 63) == 0) atomicAdd(&red[j], v);   // LDS atomic
        }
        __syncthreads();

        if (threadIdx.x == 0) {
            const float cells[3] = {819200.0f, 204800.0f, 51200.0f};
            const float npos = 512.0f;
            float lb = 0.0f, lo = 0.0f, lc = 0.0f;
            for (int s = 0; s < 3; ++s) {
                lb += red[s * 4 + 1] / npos;
                lo += (red[s * 4 + 0] + red[s * 4 + 3]) / cells[s];
                lc += red[s * 4 + 2] / (npos * 13.0f);
            }
            out[0] = 5.0f * lb + 1.0f * lo + 0.5f * lc;
            out[1] = lb;
            out[2] = lo;
            out[3] = lc;
        }
        return;
    }

    // ==================== worker blocks (wid = bid-1) ======================
    int wid = blockIdx.x - 1;
    __shared__ float sm0[4], sm1[4];
    const float* const ps[3] = {p0, p1, p2};
    const int gss[3] = {160, 80, 40};

    float v0 = 0.0f, v1 = 0.0f;

    if (wid < NBLK_BOX) {
        // ---- box + obj-correction: one thread per (target,scale) ----------
        int gid = wid * 256 + threadIdx.x;           // [0,1536)
        int s = gid >> 9;                            // block-uniform
        int t = gid & 511;

        const float bi  = tg[t * 6 + 0];
        const float cx  = tg[t * 6 + 2];
        const float cy  = tg[t * 6 + 3];
        const float w   = tg[t * 6 + 4];
        const float h   = tg[t * 6 + 5];
        const int b = (int)bi;

        const int gs = gss[s];
        const float fgs = (float)gs;
        float cxs = cx * fgs, cys = cy * fgs;
        int gi = (int)floorf(cxs); gi = min(max(gi, 0), gs - 1);
        int gj = (int)floorf(cys); gj = min(max(gj, 0), gs - 1);
        const float tx = cxs - (float)gi;
        const float ty = cys - (float)gj;
        const float tw = w * fgs;
        const float th = h * fgs;

        const int hw = gs * gs;
        const float* base = ps[s] + (size_t)b * 18 * hw + (size_t)gj * gs + gi;
        float pr0 = base[0];
        float pr1 = base[(size_t)hw];
        float pr2 = base[(size_t)2 * hw];
        float pr3 = base[(size_t)3 * hw];
        float pr4 = base[(size_t)4 * hw];

        const float px = 1.0f / (1.0f + expf(-pr0));
        const float py = 1.0f / (1.0f + expf(-pr1));
        const float pw = pr2;
        const float ph = pr3;

        const float eps = 1e-7f;
        float px1 = px - pw * 0.5f, px2 = px + pw * 0.5f;
        float py1 = py - ph * 0.5f, py2 = py + ph * 0.5f;
        float tx1 = tx - tw * 0.5f, tx2 = tx + tw * 0.5f;
        float ty1 = ty - th * 0.5f, ty2 = ty + th * 0.5f;
        float iw = fmaxf(fminf(px2, tx2) - fmaxf(px1, tx1), 0.0f);
        float ih = fmaxf(fminf(py2, ty2) - fmaxf(py1, ty1), 0.0f);
        float inter = iw * ih;
        float uni = pw * ph + tw * th - inter + eps;
        float iou = inter / uni;
        float ew = fmaxf(fmaxf(px2, tx2) - fminf(px1, tx1), 0.0f);
        float eh = fmaxf(fmaxf(py2, ty2) - fminf(py1, ty1), 0.0f);
        float c2 = ew * ew + eh * eh + eps;
        float rho2 = (px - tx) * (px - tx) + (py - ty) * (py - ty);
        const float four_over_pi2 = 0.405284734569351085775517852f;
        float dat = atanf(tw / (th + eps)) - atanf(pw / (ph + eps));
        float v = four_over_pi2 * dat * dat;
        float alpha = v / (1.0f - iou + v + eps);
        float ciou = iou - (rho2 / c2 + v * alpha);

        v0 = 1.0f - ciou;                                     // box
        float tobj = fmaxf(ciou, 0.0f);
        v1 = focal_term(pr4, tobj) - focal_term(pr4, 0.0f);   // obj corr
    } else if (wid < NBLK_TGT) {
        // ---- cls: one thread per (target,scale,class), 1 load each --------
        int g = (wid - NBLK_BOX) * 256 + threadIdx.x;
        int sk = g >> 9;          // block-uniform: (s*13 + k)
        int t  = g & 511;
        int s  = sk / 13;
        int k  = sk - s * 13;

        const float bi  = tg[t * 6 + 0];
        const float clf = tg[t * 6 + 1];
        const float cx  = tg[t * 6 + 2];
        const float cy  = tg[t * 6 + 3];
        const int b = (int)bi;
        const int cls = (int)clf;

        const int gs = gss[s];
        const float fgs = (float)gs;
        int gi = (int)floorf(cx * fgs); gi = min(max(gi, 0), gs - 1);
        int gj = (int)floorf(cy * fgs); gj = min(max(gj, 0), gs - 1);

        const int hw = gs * gs;
        float x = ps[s][(size_t)b * 18 * hw + (size_t)(5 + k) * hw +
                        (size_t)gj * gs + gi];
        float tc = (k == cls) ? 0.95f : 0.0f;
        v0 = bce_fast(x, tc);
    } else {
        // ---- focal(x,0) sweep: 512 float4 per block, 2 per thread ---------
        int chunk = wid - NBLK_TGT;                  // [0,525)
        const float* p;
        int hw4, base4;                              // block-uniform
        if (chunk < 400)      { p = p0; hw4 = 6400; base4 = 0; }
        else if (chunk < 500) { p = p1; hw4 = 1600; base4 = 204800; }
        else                  { p = p2; hw4 = 400;  base4 = 256000; }

        int j0 = chunk * 512 + threadIdx.x - base4;  // float4 idx in scale
        #pragma unroll
        for (int r = 0; r < 2; ++r) {
            int idx = j0 + r * 256;
            int b = idx / hw4;
            int pos4 = idx - b * hw4;
            int hw = hw4 * 4;
            const float4* src = reinterpret_cast<const float4*>(
                p + (size_t)b * 18 * hw + (size_t)4 * hw);
            float4 x = src[pos4];
            v0 += focal0_fast(x.x) + focal0_fast(x.y) +
                  focal0_fast(x.z) + focal0_fast(x.w);
        }
    }

    // ---- block reduce, publish via coherence-point atomics ----------------
    for (int off = 32; off; off >>= 1) {
        v0 += __shfl_down(v0, off);
        v1 += __shfl_down(v1, off);
    }
    if ((threadIdx.x & 63) == 0) {
        sm0[threadIdx.x >> 6] = v0;
        sm1[threadIdx.x >> 6] = v1;
    }
    __syncthreads();
    if (threadIdx.x == 0) {
        atomicExch(&ws[2 * wid + 0], sm0[0] + sm0[1] + sm0[2] + sm0[3]);
        atomicExch(&ws[2 * wid + 1], sm1[0] + sm1[1] + sm1[2] + sm1[3]);
        // ensure slot exchs are ack'd at the coherence point before the tag
        asm volatile("s_waitcnt vmcnt(0)" ::: "memory");
        atomicExch(&tags[wid], 1u);
    }
}

extern "C" void kernel_launch(void* const* d_in, const int* in_sizes, int n_in,
                              void* d_out, int out_size, void* d_ws, size_t ws_size,
                              hipStream_t stream) {
    const float* p0 = (const float*)d_in[0];
    const float* p1 = (const float*)d_in[1];
    const float* p2 = (const float*)d_in[2];
    const float* tg = (const float*)d_in[3];
    float* ws = (float*)d_ws;
    float* out = (float*)d_out;

    fnl_zero_tags<<<1, 640, 0, stream>>>((unsigned*)d_ws);
    fnl_fused<<<NWORK + 1, 256, 0, stream>>>(p0, p1, p2, tg, ws, out);
}